// Round 1
// 904.991 us; speedup vs baseline: 1.1506x; 1.1506x over previous
//
#include <hip/hip_runtime.h>

#define N_NODES 100000
#define N_EDGES 1600000
#define N_FEAT  602
#define HIDDEN  128
#define N_CLS   41
#define Y2_STRIDE 48   // padded rows: 192B, cache-line aligned

typedef __attribute__((ext_vector_type(8))) short bf16x8;
typedef __attribute__((ext_vector_type(4))) short s16x4;
typedef __attribute__((ext_vector_type(4))) float f32x4;

#define KPAD 608      // 19 * 32

typedef const __attribute__((address_space(1))) void gv_t;
typedef __attribute__((address_space(3))) void lv_t;

// bf16 round-to-nearest-even, returns hi and residual
__device__ inline unsigned short bf_hi(float f, float& rem) {
    unsigned int u = __float_as_uint(f);
    unsigned int r = u + 0x7FFF + ((u >> 16) & 1);
    unsigned short h = (unsigned short)(r >> 16);
    rem = f - __uint_as_float((unsigned int)h << 16);
    return h;
}
__device__ inline unsigned short bf_rn(float f) {
    unsigned int u = __float_as_uint(f);
    unsigned int r = u + 0x7FFF + ((u >> 16) & 1);
    return (unsigned short)(r >> 16);
}

// ---------------- degrees ----------------
__global__ void k_deg(const int* __restrict__ src, const int* __restrict__ dst,
                      int* __restrict__ deg_out, int* __restrict__ deg_in) {
    int e = blockIdx.x * blockDim.x + threadIdx.x;
    if (e < N_EDGES) {
        atomicAdd(&deg_out[src[e]], 1);
        atomicAdd(&deg_in[dst[e]], 1);
    }
}

__global__ void k_norm(const int* __restrict__ deg_out, const int* __restrict__ deg_in,
                       float* __restrict__ ns, float* __restrict__ nd) {
    int i = blockIdx.x * blockDim.x + threadIdx.x;
    if (i < N_NODES) {
        ns[i] = 1.0f / sqrtf((float)max(deg_out[i], 1));
        nd[i] = 1.0f / sqrtf((float)max(deg_in[i], 1));
    }
}

// ---------------- W1 convert: fp32 [602][128] -> transposed bf16 hi/lo [128][608] ----------------
__global__ void k_wconv(const float* __restrict__ W1,
                        unsigned short* __restrict__ Wt_hi,
                        unsigned short* __restrict__ Wt_lo) {
    int c = blockIdx.x;
    int k = threadIdx.x;
    if (k >= KPAD) return;
    float w = (k < N_FEAT) ? W1[(long)k * HIDDEN + c] : 0.f;
    float rem;
    unsigned short h = bf_hi(w, rem);
    Wt_hi[(long)c * KPAD + k] = h;
    Wt_lo[(long)c * KPAD + k] = bf_rn(rem);
}

// ---------------- exclusive scan of deg_in -> row_ptr ----------------
__global__ void k_scan1(const int* __restrict__ deg_in, int* __restrict__ row_ptr,
                        int* __restrict__ blk) {
    __shared__ int s[1024];
    int t = threadIdx.x;
    int i = blockIdx.x * 1024 + t;
    int v = (i < N_NODES) ? deg_in[i] : 0;
    s[t] = v; __syncthreads();
    for (int off = 1; off < 1024; off <<= 1) {
        int x = s[t];
        if (t >= off) x += s[t - off];
        __syncthreads();
        s[t] = x; __syncthreads();
    }
    if (i < N_NODES) row_ptr[i] = s[t] - v;
    if (t == 1023) blk[blockIdx.x] = s[1023];
}

__global__ void k_scan2(int* __restrict__ blk, int nblk) {
    __shared__ int s[128];
    int t = threadIdx.x;
    int v = (t < nblk) ? blk[t] : 0;
    s[t] = v; __syncthreads();
    for (int off = 1; off < 128; off <<= 1) {
        int x = s[t];
        if (t >= off) x += s[t - off];
        __syncthreads();
        s[t] = x; __syncthreads();
    }
    if (t < nblk) blk[t] = s[t] - v;
}

// also initializes cursor = row_ptr so k_fill needs no row_ptr gather
__global__ void k_scan3(int* __restrict__ row_ptr, const int* __restrict__ blk,
                        int* __restrict__ cursor) {
    int i = blockIdx.x * blockDim.x + threadIdx.x;
    if (i < N_NODES) {
        int v = row_ptr[i] + blk[i >> 10];
        row_ptr[i] = v;
        cursor[i] = v;
    }
}

// ---------------- CSR fill (bucket by dst); cursor pre-seeded with row_ptr ----------------
__global__ void k_fill(const int* __restrict__ src, const int* __restrict__ dst,
                       int* __restrict__ cursor, int* __restrict__ csr_src) {
    int e = blockIdx.x * blockDim.x + threadIdx.x;
    if (e < N_EDGES) {
        int p = atomicAdd(&cursor[dst[e]], 1);
        csr_src[p] = src[e];
    }
}

// ---------------- GEMM1 (split-bf16 MFMA) ----------------
// y1 = ns ⊙ (x @ W1). Block 128x128, 4 waves 2x2, wave 64x64 = 4x4 of 16x16x32.
// A: reg-staged fp32 -> converted ONCE per element -> bf16 hi/lo LDS tiles (64B rows,
//    conflict-free frag reads). B: precomputed bf16 hi/lo, double-buffered global_load_lds.
// Next-tile A loads + B stages issued during MFMA phase (latency hidden under compute).
__global__ __launch_bounds__(256, 3) void k_gemm1(const float* __restrict__ x,
                                                  const unsigned short* __restrict__ Wt_hi,
                                                  const unsigned short* __restrict__ Wt_lo,
                                                  const float* __restrict__ ns,
                                                  float* __restrict__ y1) {
    __shared__ __align__(16) unsigned short Ah[128 * 32];      // 8 KB
    __shared__ __align__(16) unsigned short Al[128 * 32];      // 8 KB
    __shared__ __align__(16) unsigned short Bh[2][128 * 32];   // 16 KB
    __shared__ __align__(16) unsigned short Bl[2][128 * 32];   // 16 KB

    int tid = threadIdx.x;
    int lane = tid & 63;
    int wave = tid >> 6;
    int quad = lane >> 4, l16 = lane & 15;
    int wm = wave >> 1, wn = wave & 1;
    int m0 = blockIdx.x * 128;

    f32x4 acc[4][4];
    #pragma unroll
    for (int i = 0; i < 4; i++)
        #pragma unroll
        for (int j = 0; j < 4; j++)
            acc[i][j] = (f32x4){0.f, 0.f, 0.f, 0.f};

    // A: instr i, lane l -> row = wave*32 + i*8 + l/8, chunk = l%8 (4 fp32)
    int a_row = wave * 32 + (lane >> 3);
    int a_chn = lane & 7;
    // B staging: instr i, lane l -> col = wave*32 + i*16 + l/4, chunk = l%4 (16B bf16)
    int b_col = wave * 32 + (lane >> 2);
    int b_chn = lane & 3;

    float4 av[4];

    auto loadA = [&](int kt) {
        int k0 = kt * 32;
        #pragma unroll
        for (int i = 0; i < 4; ++i) {
            long rowg = min(m0 + a_row + i * 8, N_NODES - 1);   // clamp rows (addr validity)
            av[i] = *(const float4*)(x + rowg * N_FEAT + k0 + a_chn * 4);
        }
    };
    auto loadB = [&](int kt, int buf) {
        int k0 = kt * 32;
        #pragma unroll
        for (int i = 0; i < 2; ++i) {
            int col = b_col + i * 16;
            long g = (long)col * KPAD + k0 + b_chn * 8;
            __builtin_amdgcn_global_load_lds((gv_t*)(Wt_hi + g), (lv_t*)&Bh[buf][wave * 1024 + i * 512], 16, 0, 0);
            __builtin_amdgcn_global_load_lds((gv_t*)(Wt_lo + g), (lv_t*)&Bl[buf][wave * 1024 + i * 512], 16, 0, 0);
        }
    };

    loadA(0);
    loadB(0, 0);

    for (int kt = 0; kt < 19; ++kt) {
        int cur = kt & 1;

        // ---- convert staged A regs -> bf16 hi/lo LDS (once per element) ----
        #pragma unroll
        for (int i = 0; i < 4; ++i) {
            float4 f = av[i];
            if (kt == 18) {
                // zero k = 602..607 (tile covers 576..607; garbage past row end)
                int kb = a_chn * 4;
                if (kb + 0 >= 26) f.x = 0.f;
                if (kb + 1 >= 26) f.y = 0.f;
                if (kb + 2 >= 26) f.z = 0.f;
                if (kb + 3 >= 26) f.w = 0.f;
            }
            s16x4 h, l;
            float rem;
            h[0] = (short)bf_hi(f.x, rem); l[0] = (short)bf_rn(rem);
            h[1] = (short)bf_hi(f.y, rem); l[1] = (short)bf_rn(rem);
            h[2] = (short)bf_hi(f.z, rem); l[2] = (short)bf_rn(rem);
            h[3] = (short)bf_hi(f.w, rem); l[3] = (short)bf_rn(rem);
            int rl = a_row + i * 8;
            *(s16x4*)&Ah[rl * 32 + a_chn * 4] = h;
            *(s16x4*)&Al[rl * 32 + a_chn * 4] = l;
        }
        __syncthreads();   // A writes + B(kt) staging visible

        // ---- prefetch next tile while MFMAs run ----
        if (kt < 18) {
            loadA(kt + 1);
            loadB(kt + 1, cur ^ 1);
        }

        // ---- fragments + MFMA (B frags hoisted out of mi loop) ----
        bf16x8 bh[4], bl[4];
        #pragma unroll
        for (int ni = 0; ni < 4; ++ni) {
            int bc = wn * 64 + ni * 16 + l16;
            bh[ni] = *(bf16x8*)&Bh[cur][bc * 32 + quad * 8];
            bl[ni] = *(bf16x8*)&Bl[cur][bc * 32 + quad * 8];
        }
        #pragma unroll
        for (int mi = 0; mi < 4; ++mi) {
            int ar = wm * 64 + mi * 16 + l16;
            bf16x8 ah = *(bf16x8*)&Ah[ar * 32 + quad * 8];
            bf16x8 al = *(bf16x8*)&Al[ar * 32 + quad * 8];
            #pragma unroll
            for (int ni = 0; ni < 4; ++ni) {
                acc[mi][ni] = __builtin_amdgcn_mfma_f32_16x16x32_bf16(ah, bh[ni], acc[mi][ni], 0, 0, 0);
                acc[mi][ni] = __builtin_amdgcn_mfma_f32_16x16x32_bf16(al, bh[ni], acc[mi][ni], 0, 0, 0);
                acc[mi][ni] = __builtin_amdgcn_mfma_f32_16x16x32_bf16(ah, bl[ni], acc[mi][ni], 0, 0, 0);
            }
        }
        __syncthreads();   // Ah/Al reads done before next convert's writes
    }

    // epilogue: C/D layout col=lane&15, row=quad*4+reg
    #pragma unroll
    for (int mi = 0; mi < 4; ++mi) {
        #pragma unroll
        for (int r = 0; r < 4; ++r) {
            int row = m0 + wm * 64 + mi * 16 + quad * 4 + r;
            if (row < N_NODES) {
                float s = ns[row];
                #pragma unroll
                for (int ni = 0; ni < 4; ++ni) {
                    int col = wn * 64 + ni * 16 + l16;
                    y1[(long)row * HIDDEN + col] = acc[mi][ni][r] * s;
                }
            }
        }
    }
}

// ---------------- SpMM1 + epilogue: h1 = relu(A@y1 * nd + b1) ----------------
// unroll x4 with independent accumulators -> 4 row-gathers in flight per wave
__global__ __launch_bounds__(256) void k_spmm1(const float* __restrict__ y1,
                                               const int* __restrict__ row_ptr,
                                               const int* __restrict__ deg_in,
                                               const int* __restrict__ csr_src,
                                               const float* __restrict__ nd,
                                               const float* __restrict__ b1,
                                               float* __restrict__ h1) {
    int wave = threadIdx.x >> 6, lane = threadIdx.x & 63;
    int n = blockIdx.x * 4 + wave;
    if (n >= N_NODES) return;
    int base = row_ptr[n], deg = deg_in[n];
    const float2* yp = (const float2*)y1;
    float a0 = 0.f, a1 = 0.f, b0 = 0.f, b1v = 0.f;
    float c0 = 0.f, c1 = 0.f, d0 = 0.f, d1 = 0.f;
    int j = 0;
    for (; j + 4 <= deg; j += 4) {
        int s0 = csr_src[base + j];
        int s1 = csr_src[base + j + 1];
        int s2 = csr_src[base + j + 2];
        int s3 = csr_src[base + j + 3];
        float2 v0 = yp[(long)s0 * 64 + lane];
        float2 v1 = yp[(long)s1 * 64 + lane];
        float2 v2 = yp[(long)s2 * 64 + lane];
        float2 v3 = yp[(long)s3 * 64 + lane];
        a0 += v0.x; a1 += v0.y;
        b0 += v1.x; b1v += v1.y;
        c0 += v2.x; c1 += v2.y;
        d0 += v3.x; d1 += v3.y;
    }
    for (; j < deg; ++j) {
        int s = csr_src[base + j];
        float2 v = yp[(long)s * 64 + lane];
        a0 += v.x; a1 += v.y;
    }
    a0 = (a0 + b0) + (c0 + d0);
    a1 = (a1 + b1v) + (c1 + d1);
    float d = nd[n];
    float2 b = ((const float2*)b1)[lane];
    float2 r;
    r.x = fmaxf(a0 * d + b.x, 0.f);
    r.y = fmaxf(a1 * d + b.y, 0.f);
    ((float2*)(h1 + (long)n * HIDDEN))[lane] = r;
}

// ---------------- GEMM2: y2 = ns ⊙ (h1 @ W2), padded rows (stride 48) ----------------
__global__ __launch_bounds__(256) void k_gemm2(const float* __restrict__ h1,
                                               const float* __restrict__ W2,
                                               const float* __restrict__ ns,
                                               float* __restrict__ y2) {
    __shared__ float sz[64 * 132];
    __shared__ float sw[128 * 44];
    int tid = threadIdx.x;
    int m0 = blockIdx.x * 64;
    for (int idx = tid; idx < 128 * 44; idx += 256) {
        int k = idx / 44, c = idx % 44;
        sw[idx] = (c < N_CLS) ? W2[k * N_CLS + c] : 0.f;
    }
    for (int idx = tid; idx < 64 * 32; idx += 256) {
        int r = idx >> 5, q = idx & 31;
        int row = m0 + r;
        float4 v = make_float4(0.f, 0.f, 0.f, 0.f);
        if (row < N_NODES) v = ((const float4*)h1)[(long)row * 32 + q];
        *((float4*)&sz[r * 132 + q * 4]) = v;
    }
    __syncthreads();
    int r = tid >> 2, cq = tid & 3;
    int c0 = cq * 11;
    float acc[11];
    #pragma unroll
    for (int j = 0; j < 11; j++) acc[j] = 0.f;
    #pragma unroll 8
    for (int k = 0; k < 128; ++k) {
        float a = sz[r * 132 + k];
        #pragma unroll
        for (int j = 0; j < 11; j++) acc[j] = fmaf(a, sw[k * 44 + c0 + j], acc[j]);
    }
    int row = m0 + r;
    if (row < N_NODES) {
        float s = ns[row];
        #pragma unroll
        for (int j = 0; j < 11; j++) {
            int c = c0 + j;
            if (c < N_CLS) y2[(long)row * Y2_STRIDE + c] = acc[j] * s;
        }
    }
}

// ---------------- SpMM2 + epilogue: out = A@y2 * nd + b2 ----------------
__global__ __launch_bounds__(256) void k_spmm2(const float* __restrict__ y2,
                                               const int* __restrict__ row_ptr,
                                               const int* __restrict__ deg_in,
                                               const int* __restrict__ csr_src,
                                               const float* __restrict__ nd,
                                               const float* __restrict__ b2,
                                               float* __restrict__ out) {
    int wave = threadIdx.x >> 6, lane = threadIdx.x & 63;
    int n = blockIdx.x * 4 + wave;
    if (n >= N_NODES) return;
    if (lane >= N_CLS) return;
    int base = row_ptr[n], deg = deg_in[n];
    float a = 0.f, b = 0.f, c = 0.f, d = 0.f;
    int j = 0;
    for (; j + 4 <= deg; j += 4) {
        int s0 = csr_src[base + j];
        int s1 = csr_src[base + j + 1];
        int s2 = csr_src[base + j + 2];
        int s3 = csr_src[base + j + 3];
        a += y2[(long)s0 * Y2_STRIDE + lane];
        b += y2[(long)s1 * Y2_STRIDE + lane];
        c += y2[(long)s2 * Y2_STRIDE + lane];
        d += y2[(long)s3 * Y2_STRIDE + lane];
    }
    for (; j < deg; ++j) {
        int s = csr_src[base + j];
        a += y2[(long)s * Y2_STRIDE + lane];
    }
    a = (a + b) + (c + d);
    out[(long)n * N_CLS + lane] = a * nd[n] + b2[lane];
}

extern "C" void kernel_launch(void* const* d_in, const int* in_sizes, int n_in,
                              void* d_out, int out_size, void* d_ws, size_t ws_size,
                              hipStream_t stream) {
    const float* x    = (const float*)d_in[0];
    const int*   esrc = (const int*)d_in[1];
    const int*   edst = (const int*)d_in[2];
    const float* W1   = (const float*)d_in[3];
    const float* b1   = (const float*)d_in[4];
    const float* W2   = (const float*)d_in[5];
    const float* b2   = (const float*)d_in[6];
    float* out = (float*)d_out;

    char* p = (char*)d_ws;
    auto alloc = [&](size_t bytes) {
        char* r = p;
        p += (bytes + 255) & ~(size_t)255;
        return r;
    };
    int*   deg_out = (int*)alloc((size_t)N_NODES * 4);
    int*   deg_in  = (int*)alloc((size_t)N_NODES * 4);
    float* ns      = (float*)alloc((size_t)N_NODES * 4);
    float* nd      = (float*)alloc((size_t)N_NODES * 4);
    int*   row_ptr = (int*)alloc((size_t)N_NODES * 4);
    int*   cursor  = (int*)alloc((size_t)N_NODES * 4);
    int*   blk     = (int*)alloc(1024 * 4);
    unsigned short* Wt_hi = (unsigned short*)alloc((size_t)HIDDEN * KPAD * 2);
    unsigned short* Wt_lo = (unsigned short*)alloc((size_t)HIDDEN * KPAD * 2);
    int*   csr     = (int*)alloc((size_t)N_EDGES * 4);
    float* y1      = (float*)alloc((size_t)N_NODES * HIDDEN * 4);  // reused as y2 (stride 48 fits)
    float* h1      = (float*)alloc((size_t)N_NODES * HIDDEN * 4);
    float* y2      = y1;
    if ((size_t)(p - (char*)d_ws) > ws_size) return;

    hipMemsetAsync(deg_out, 0, (size_t)N_NODES * 4, stream);
    hipMemsetAsync(deg_in,  0, (size_t)N_NODES * 4, stream);

    const int EB = (N_EDGES + 255) / 256;
    const int NB = (N_NODES + 255) / 256;
    const int SB = (N_NODES + 1023) / 1024;
    const int MB = (N_NODES + 127) / 128;

    k_deg<<<EB, 256, 0, stream>>>(esrc, edst, deg_out, deg_in);
    k_norm<<<NB, 256, 0, stream>>>(deg_out, deg_in, ns, nd);
    k_wconv<<<HIDDEN, 640, 0, stream>>>(W1, Wt_hi, Wt_lo);
    k_scan1<<<SB, 1024, 0, stream>>>(deg_in, row_ptr, blk);
    k_scan2<<<1, 128, 0, stream>>>(blk, SB);
    k_scan3<<<NB, 256, 0, stream>>>(row_ptr, blk, cursor);
    k_fill<<<EB, 256, 0, stream>>>(esrc, edst, cursor, csr);
    k_gemm1<<<MB, 256, 0, stream>>>(x, Wt_hi, Wt_lo, ns, y1);
    k_spmm1<<<(N_NODES + 3) / 4, 256, 0, stream>>>(y1, row_ptr, deg_in, csr, nd, b1, h1);
    k_gemm2<<<(N_NODES + 63) / 64, 256, 0, stream>>>(h1, W2, ns, y2);
    k_spmm2<<<(N_NODES + 3) / 4, 256, 0, stream>>>(y2, row_ptr, deg_in, csr, nd, b2, out);
}